// Round 7
// baseline (565.321 us; speedup 1.0000x reference)
//
#include <hip/hip_runtime.h>
#include <stdint.h>

// One chain per 64-thread block (one wave). No __syncthreads anywhere: all
// LDS producer->consumer dependencies are intra-wave, ordered by lgkmcnt.
//
// Each 64x64 matrix: bf16 planes in LDS, unpadded stride 64, XOR-swizzled:
//   element [r][c] at short-index  r*64 + (((c>>3) ^ (r&7))<<3) + (c&7)
//   R-plane: row-major  (MFMA A-fragment = one b128)
//   T-plane: transposed (MFMA B-fragment = one b128)
#define PL 4096  // shorts per plane (8 KB)

typedef unsigned int u32;
typedef unsigned short u16;
typedef float f32x4 __attribute__((ext_vector_type(4)));
typedef short short8 __attribute__((ext_vector_type(8)));

__device__ __forceinline__ u32 prm(u32 a, u32 b, u32 s) {
  return __builtin_amdgcn_perm(a, b, s);
}
__device__ __forceinline__ u32 pk(float f0, float f1) {  // {bf16 f0, bf16 f1}
  return prm(__float_as_uint(f1), __float_as_uint(f0), 0x07060302u);
}
__device__ __forceinline__ float rlo(u32 w) { return __uint_as_float(w << 16); }
__device__ __forceinline__ float rhi(u32 w) {
  return __uint_as_float(w & 0xffff0000u);
}

// Per-lane invariant LDS short-offsets.
struct O {
  int fr[4][2];  // fragment read (same formula for A from R and B from T)
  int sb[4];     // store row base [tile index]
  int xr[4];     // store swizzled col-run offset [tile index]
  int prow[8];   // elementwise: R-ish access, row 8rb+i, col-block cb
  int pcol[8];   // elementwise: T-plane store, row 8cb+j, col-block rb
};

// C = A @ B (64x64 bf16), whole product by ONE wave: 4x4 grid of 16x16 MFMA
// tiles. Primary product (a x b) -> D is C^T-contiguous -> T-plane; mirror
// (b x a) -> C-contiguous -> R-plane. WR/WT gate dead planes. No barrier.
template <bool WR, bool WT>
__device__ __forceinline__ void mm(const u16* __restrict__ AR,
                                   const u16* __restrict__ BT,
                                   u16* __restrict__ CR, u16* __restrict__ CT,
                                   const O& o) {
  short8 a[4][2], b[4][2];
#pragma unroll
  for (int t = 0; t < 4; ++t)
#pragma unroll
    for (int q = 0; q < 2; ++q) {
      a[t][q] = *(const short8*)(AR + o.fr[t][q]);
      b[t][q] = *(const short8*)(BT + o.fr[t][q]);
    }
  const f32x4 Z = {0.0f, 0.0f, 0.0f, 0.0f};
#pragma unroll
  for (int ti = 0; ti < 4; ++ti)
#pragma unroll
    for (int tj = 0; tj < 4; ++tj) {
      if (WT) {
        f32x4 acc = __builtin_amdgcn_mfma_f32_16x16x32_bf16(a[ti][0], b[tj][0],
                                                            Z, 0, 0, 0);
        acc = __builtin_amdgcn_mfma_f32_16x16x32_bf16(a[ti][1], b[tj][1], acc,
                                                      0, 0, 0);
        *(uint2*)(CT + o.sb[tj] + o.xr[ti]) =
            make_uint2(pk(acc[0], acc[1]), pk(acc[2], acc[3]));
      }
      if (WR) {
        f32x4 acc = __builtin_amdgcn_mfma_f32_16x16x32_bf16(b[tj][0], a[ti][0],
                                                            Z, 0, 0, 0);
        acc = __builtin_amdgcn_mfma_f32_16x16x32_bf16(b[tj][1], a[ti][1], acc,
                                                      0, 0, 0);
        *(uint2*)(CR + o.sb[ti] + o.xr[tj]) =
            make_uint2(pk(acc[0], acc[1]), pk(acc[2], acc[3]));
      }
    }
}

// Schedule per iter (verified in R6; 6 plane slots, invariant carried
// {PA=R15, PB=T15, PC=T3} of the current matrix):
//   front: m30:(PA,PB)->PD,PE  m60:(PD,PE)->PA[R]  m63:(PA,PC)->PB[T]
//   gradprox (reads T63=PB, alpha from trace reg); stage m(new x)->PD,PE
//   chain5: m2:(PD,PE)->PF[R]  m3:(PF,PE)->PA,PC  m6:(PA,PC)->PD,PE
//           m12:(PD,PE)->PF[R] m15:(PF,PC)->PA,PB  trace=sum R15.*T15
__global__ __launch_bounds__(64) void dag_iter_kernel(
    const float* __restrict__ adj, float* __restrict__ out) {
  __shared__ __align__(16) u16 BUF[6 * PL];
  u16* PA = BUF;
  u16* PB = BUF + PL;
  u16* PC = BUF + 2 * PL;
  u16* PD = BUF + 3 * PL;
  u16* PE = BUF + 4 * PL;
  u16* PF = BUF + 5 * PL;

  const int lane = (int)threadIdx.x;  // 0..63
  const int l15 = lane & 15;
  const int grp = lane >> 4;
  const int l7 = l15 & 7;
  const int rb = lane >> 3;  // elementwise 8x8 block: rows 8rb..8rb+7
  const int cb = lane & 7;   //                        cols 8cb..8cb+7

  O o;
#pragma unroll
  for (int q = 0; q < 2; ++q) {
    const int koff = ((((q << 2) + grp)) ^ l7) << 3;
#pragma unroll
    for (int t = 0; t < 4; ++t) o.fr[t][q] = (16 * t + l15) * 64 + koff;
  }
#pragma unroll
  for (int t = 0; t < 4; ++t) {
    o.sb[t] = (16 * t + l15) * 64 + ((grp & 1) << 2);
    o.xr[t] = (((2 * t + (grp >> 1)) ^ l7) << 3);
  }
#pragma unroll
  for (int i = 0; i < 8; ++i) {
    o.prow[i] = (8 * rb + i) * 64 + ((cb ^ i) << 3);
    o.pcol[i] = (8 * cb + i) * 64 + ((rb ^ i) << 3);
  }

  const float* src = adj + (size_t)blockIdx.x * 4096;
  float x[8][8];
  u32 scp[8][4];  // scores, packed bf16 pairs (cols 2k,2k+1)
#pragma unroll
  for (int i = 0; i < 8; ++i) {
    f32x4 v0 = *(const f32x4*)(src + (8 * rb + i) * 64 + 8 * cb);
    f32x4 v1 = *(const f32x4*)(src + (8 * rb + i) * 64 + 8 * cb + 4);
    float s[8];
#pragma unroll
    for (int j = 0; j < 4; ++j) {
      x[i][j] = v0[j];
      x[i][j + 4] = v1[j];
    }
#pragma unroll
    for (int j = 0; j < 8; ++j) s[j] = (x[i][j] > 0.5f) ? x[i][j] : 0.0f;
#pragma unroll
    for (int k = 0; k < 4; ++k) scp[i][k] = pk(s[2 * k], s[2 * k + 1]);
  }
  float alpha = 0.0f;
  float trval = 0.0f;

  auto prox = [&](float til[8][8]) {
#pragma unroll
    for (int i = 0; i < 8; ++i)
#pragma unroll
      for (int j = 0; j < 8; ++j) {
        float ax = fabsf(til[i][j]) - 2e-5f;
        float nx = ax > 0.0f ? ax : 0.0f;
        x[i][j] = nx > 1.0f ? 1.0f : nx;
      }
  };
  auto stage = [&]() {  // m = I + x.*x/64 -> PD (R-plane), PE (T-plane)
    float m[8][8];
#pragma unroll
    for (int i = 0; i < 8; ++i)
#pragma unroll
      for (int j = 0; j < 8; ++j)
        m[i][j] = fmaf(x[i][j] * x[i][j], 0.015625f,
                       (rb == cb && i == j) ? 1.0f : 0.0f);
#pragma unroll
    for (int i = 0; i < 8; ++i) {
      int4 v;
      v.x = (int)pk(m[i][0], m[i][1]);
      v.y = (int)pk(m[i][2], m[i][3]);
      v.z = (int)pk(m[i][4], m[i][5]);
      v.w = (int)pk(m[i][6], m[i][7]);
      *(int4*)(PD + o.prow[i]) = v;
    }
#pragma unroll
    for (int j = 0; j < 8; ++j) {
      int4 v;
      v.x = (int)pk(m[0][j], m[1][j]);
      v.y = (int)pk(m[2][j], m[3][j]);
      v.z = (int)pk(m[4][j], m[5][j]);
      v.w = (int)pk(m[6][j], m[7][j]);
      *(int4*)(PE + o.pcol[j]) = v;
    }
  };
  auto chain5 = [&]() {  // after stage; leaves PA=R15, PB=T15, PC=T3
    mm<true, false>(PD, PE, PF, PF, o);  // m2  -> R only
    mm<true, true>(PF, PE, PA, PC, o);   // m3  = m2*m
    mm<true, true>(PA, PC, PD, PE, o);   // m6  = m3^2
    mm<true, false>(PD, PE, PF, PF, o);  // m12 -> R only
    mm<true, true>(PF, PC, PA, PB, o);   // m15 = m12*m3
    // trace(m^30) = sum_elem R15 .* T15 (same swizzled addressing)
    float part = 0.0f;
#pragma unroll
    for (int i = 0; i < 8; ++i) {
      int4 a = *(const int4*)(PA + o.prow[i]);
      int4 b = *(const int4*)(PB + o.prow[i]);
      const u32* ap = (const u32*)&a;
      const u32* bp = (const u32*)&b;
#pragma unroll
      for (int w = 0; w < 4; ++w) {
        part = fmaf(rlo(ap[w]), rlo(bp[w]), part);
        part = fmaf(rhi(ap[w]), rhi(bp[w]), part);
      }
    }
#pragma unroll
    for (int off = 1; off < 64; off <<= 1) part += __shfl_xor(part, off);
    trval = part;
  };
  auto gradprox = [&]() {  // uses T63 in PB; alpha from trval
    alpha = fmaf(0.01f, trval * 0.015625f - 1.0f, alpha);
    const float a2 = alpha * 0.03125f;  // 2*alpha/64
    float til[8][8];
#pragma unroll
    for (int i = 0; i < 8; ++i) {
      int4 w = *(const int4*)(PB + o.prow[i]);
      const u32* wp = (const u32*)&w;
#pragma unroll
      for (int k = 0; k < 4; ++k) {
        float ptA = rlo(wp[k]);
        float ptB = rhi(wp[k]);
        float scA = rlo(scp[i][k]);
        float scB = rhi(scp[i][k]);
        float gA = fmaf(a2 * x[i][2 * k], ptA, -scA);
        float gB = fmaf(a2 * x[i][2 * k + 1], ptB, -scB);
        til[i][2 * k] = fmaf(-0.01f, gA, x[i][2 * k]);
        til[i][2 * k + 1] = fmaf(-0.01f, gB, x[i][2 * k + 1]);
      }
    }
    prox(til);
  };

  // ---- iteration 0: alpha == 0 -> grad = -scores ----
  {
    float til[8][8];
#pragma unroll
    for (int i = 0; i < 8; ++i)
#pragma unroll
      for (int k = 0; k < 4; ++k) {
        til[i][2 * k] = fmaf(0.01f, rlo(scp[i][k]), x[i][2 * k]);
        til[i][2 * k + 1] = fmaf(0.01f, rhi(scp[i][k]), x[i][2 * k + 1]);
      }
    prox(til);
    stage();
    chain5();
  }
  // ---- iterations 1..48 ----
  for (int it = 0; it < 48; ++it) {
    mm<true, true>(PA, PB, PD, PE, o);   // m30 = m15^2
    mm<true, false>(PD, PE, PA, PA, o);  // m60 -> R only
    mm<false, true>(PA, PC, PB, PB, o);  // m63 = m60*m3 -> T only
    gradprox();
    stage();
    chain5();
  }
  // ---- iteration 49: no trailing trace chain ----
  mm<true, true>(PA, PB, PD, PE, o);
  mm<true, false>(PD, PE, PA, PA, o);
  mm<false, true>(PA, PC, PB, PB, o);
  gradprox();

  float* dst = out + (size_t)blockIdx.x * 4096;
#pragma unroll
  for (int i = 0; i < 8; ++i) {
    f32x4 v0, v1;
#pragma unroll
    for (int j = 0; j < 4; ++j) {
      v0[j] = (x[i][j] > 0.5f) ? x[i][j] : 0.0f;
      v1[j] = (x[i][j + 4] > 0.5f) ? x[i][j + 4] : 0.0f;
    }
    *(f32x4*)(dst + (8 * rb + i) * 64 + 8 * cb) = v0;
    *(f32x4*)(dst + (8 * rb + i) * 64 + 8 * cb + 4) = v1;
  }
}

extern "C" void kernel_launch(void* const* d_in, const int* in_sizes, int n_in,
                              void* d_out, int out_size, void* d_ws,
                              size_t ws_size, hipStream_t stream) {
  const float* adj = (const float*)d_in[0];
  float* out = (float*)d_out;
  const int nbatch = in_sizes[0] / 4096;  // 512
  dag_iter_kernel<<<nbatch, 64, 0, stream>>>(adj, out);
}

// Round 8
// 267.785 us; speedup vs baseline: 2.1111x; 2.1111x over previous
//
#include <hip/hip_runtime.h>
#include <stdint.h>

// Each 64x64 matrix: bf16 planes in LDS, unpadded stride 64, XOR-swizzled:
//   element [r][c] at short-index  r*64 + (((c>>3) ^ (r&7))<<3) + (c&7)
//   R-plane: row-major (MFMA A-fragment = one b128)
//   T-plane: transposed (MFMA B-fragment = one b128)
// 6 fixed plane slots, 1-periodic schedule; all LDS addrs loop-invariant.
#define PL 4096  // shorts per plane

typedef unsigned int u32;
typedef unsigned short u16;
typedef float f32x4 __attribute__((ext_vector_type(4)));
typedef short short8 __attribute__((ext_vector_type(8)));

__device__ __forceinline__ u32 prm(u32 a, u32 b, u32 s) {
  return __builtin_amdgcn_perm(a, b, s);
}
__device__ __forceinline__ u32 pk(float f0, float f1) {  // {bf16 f0, bf16 f1}
  return prm(__float_as_uint(f1), __float_as_uint(f0), 0x07060302u);
}
__device__ __forceinline__ float rlo(u32 w) { return __uint_as_float(w << 16); }
__device__ __forceinline__ float rhi(u32 w) {
  return __uint_as_float(w & 0xffff0000u);
}

// Per-thread invariant LDS short-offsets (4-wave 2x2 quadrant split).
struct O {
  int ra[2][2];  // A-frag read [ti][q]
  int rb[2][2];  // B-frag read [tj][q]
  int sT[2][2];  // T-plane store for primary product tile (ti,tj)
  int sR[2][2];  // R-plane store for mirror product tile (ti,tj)
  int prow[4];   // patch addr: sidx(r0+i, c0), 4-elem run
  int pcol[4];   // patch addr: sidx(c0+j, r0), 4-elem run
};

// C = A @ B (64x64 bf16). 4 waves, wave wv owns quadrant as 2x2 16x16 tiles.
// Primary (a x b) -> C^T-contiguous -> T-plane; mirror (b x a) -> R-plane.
// WR/WT gate dead planes. TR: the two diagonal waves (0,3) also compute the
// elementwise sum  sum R.*T  from the already-loaded fragments (their a/b
// fragment index sets coincide element-for-element), i.e. tr(A*B) when
// A=R15,B=T15 -> tr(m30) for free. Dest planes != source planes. Barrier.
template <bool WR, bool WT, bool TR = false>
__device__ __forceinline__ void mm(const u16* __restrict__ AR,
                                   const u16* __restrict__ BT,
                                   u16* __restrict__ CR, u16* __restrict__ CT,
                                   const O& o, float* red = nullptr) {
  short8 a0[2], a1[2], b0[2], b1[2];
#pragma unroll
  for (int t = 0; t < 2; ++t) {
    a0[t] = *(const short8*)(AR + o.ra[t][0]);
    a1[t] = *(const short8*)(AR + o.ra[t][1]);
    b0[t] = *(const short8*)(BT + o.rb[t][0]);
    b1[t] = *(const short8*)(BT + o.rb[t][1]);
  }
  if (TR) {
    const int tid = (int)threadIdx.x;
    const int wvv = tid >> 6;
    if (wvv == 0 || wvv == 3) {  // diagonal quadrants: frags element-aligned
      float part = 0.0f;
#pragma unroll
      for (int t = 0; t < 2; ++t) {
        const u32* ap0 = (const u32*)&a0[t];
        const u32* bp0 = (const u32*)&b0[t];
        const u32* ap1 = (const u32*)&a1[t];
        const u32* bp1 = (const u32*)&b1[t];
#pragma unroll
        for (int w = 0; w < 4; ++w) {
          part = fmaf(rlo(ap0[w]), rlo(bp0[w]), part);
          part = fmaf(rhi(ap0[w]), rhi(bp0[w]), part);
          part = fmaf(rlo(ap1[w]), rlo(bp1[w]), part);
          part = fmaf(rhi(ap1[w]), rhi(bp1[w]), part);
        }
      }
#pragma unroll
      for (int off = 1; off < 64; off <<= 1) part += __shfl_xor(part, off);
      if ((tid & 63) == 0) red[wvv == 0 ? 0 : 1] = part;
    }
  }
  const f32x4 Z = {0.0f, 0.0f, 0.0f, 0.0f};
#pragma unroll
  for (int ti = 0; ti < 2; ++ti)
#pragma unroll
    for (int tj = 0; tj < 2; ++tj) {
      if (WT) {
        f32x4 acc = __builtin_amdgcn_mfma_f32_16x16x32_bf16(a0[ti], b0[tj], Z,
                                                            0, 0, 0);
        acc = __builtin_amdgcn_mfma_f32_16x16x32_bf16(a1[ti], b1[tj], acc, 0,
                                                      0, 0);
        *(uint2*)(CT + o.sT[ti][tj]) =
            make_uint2(pk(acc[0], acc[1]), pk(acc[2], acc[3]));
      }
      if (WR) {
        f32x4 acc = __builtin_amdgcn_mfma_f32_16x16x32_bf16(b0[tj], a0[ti], Z,
                                                            0, 0, 0);
        acc = __builtin_amdgcn_mfma_f32_16x16x32_bf16(b1[tj], a1[ti], acc, 0,
                                                      0, 0);
        *(uint2*)(CR + o.sR[ti][tj]) =
            make_uint2(pk(acc[0], acc[1]), pk(acc[2], acc[3]));
      }
    }
  __syncthreads();
}

// One block (256 thr = 4 waves) per batch element; 2 blocks/CU. Thread owns a
// 4x4 patch (r0=(tid&15)*4, c0=(tid>>4)*4) for elementwise work.
//
// 1-periodic 6-slot schedule, invariant entering each iter:
//   PA=R15, PB=T15, PC=T3  (of current x)
//   f1 m30:(PA,PB)->(PD,PE) [+free trace into red]   f2 m60:(PD,PE)->PF [R]
//   f3 m63:(PF,PC)->PD [T]
//   g: gradprox (alpha from red, T63 from PD); stage m(new x)->(PE=R, PF=T)
//   c1 m2:(PE,PF)->PD [R]      c2 m3:(PD,PF)->(PE=R3, PC=T3)
//   c3 m6:(PE,PC)->(PD,PF)     c4 m12:(PD,PF)->PE [R]
//   c5 m15:(PE,PC)->(PA,PB)
__global__ __launch_bounds__(256, 2) void dag_iter_kernel(
    const float* __restrict__ adj, float* __restrict__ out) {
  __shared__ __align__(16) u16 BUF[6 * PL];
  __shared__ float red[2];
  u16* PA = BUF;
  u16* PB = BUF + PL;
  u16* PC = BUF + 2 * PL;
  u16* PD = BUF + 3 * PL;
  u16* PE = BUF + 4 * PL;
  u16* PF = BUF + 5 * PL;

  // De-phase the two co-resident blocks (b and b+256 share a CU under
  // round-robin dispatch): offset the second wavefront-of-blocks by ~half a
  // round so their LDS bursts interleave instead of colliding.
  if ((blockIdx.x >> 8) & 1) __builtin_amdgcn_s_sleep(11);

  const int tid = (int)threadIdx.x;
  const int lane = tid & 63;
  const int wv = tid >> 6;
  const int rh4 = (wv >> 1) << 1;
  const int ch4 = (wv & 1) << 1;
  const int l15 = lane & 15;
  const int grp = lane >> 4;
  const int l7 = l15 & 7;
  const int r0 = (tid & 15) << 2;
  const int c0 = (tid >> 4) << 2;

  O o;
#pragma unroll
  for (int q = 0; q < 2; ++q) {
    const int koff = (((q << 2) + grp) ^ l7) << 3;
#pragma unroll
    for (int t = 0; t < 2; ++t) {
      o.ra[t][q] = ((rh4 + t) * 16 + l15) * 64 + koff;
      o.rb[t][q] = ((ch4 + t) * 16 + l15) * 64 + koff;
    }
  }
#pragma unroll
  for (int ti = 0; ti < 2; ++ti)
#pragma unroll
    for (int tj = 0; tj < 2; ++tj) {
      const int a = rh4 + ti;
      const int b = ch4 + tj;
      o.sT[ti][tj] = (16 * b + l15) * 64 +
                     (((2 * a + (grp >> 1)) ^ l7) << 3) + ((grp & 1) << 2);
      o.sR[ti][tj] = (16 * a + l15) * 64 +
                     (((2 * b + (grp >> 1)) ^ l7) << 3) + ((grp & 1) << 2);
    }
#pragma unroll
  for (int i = 0; i < 4; ++i) {
    o.prow[i] =
        (r0 + i) * 64 + ((((c0 >> 3) ^ ((r0 + i) & 7))) << 3) + (c0 & 7);
    o.pcol[i] =
        (c0 + i) * 64 + ((((r0 >> 3) ^ ((c0 + i) & 7))) << 3) + (r0 & 7);
  }

  const float* src = adj + (size_t)blockIdx.x * 4096;
  float x[4][4], sc[4][4];
#pragma unroll
  for (int i = 0; i < 4; ++i) {
    f32x4 v = *(const f32x4*)(src + (r0 + i) * 64 + c0);
#pragma unroll
    for (int j = 0; j < 4; ++j) {
      x[i][j] = v[j];
      sc[i][j] = (v[j] > 0.5f) ? v[j] : 0.0f;
    }
  }
  float alpha = 0.0f;

  auto prox = [&](float til[4][4]) {
#pragma unroll
    for (int i = 0; i < 4; ++i)
#pragma unroll
      for (int j = 0; j < 4; ++j) {
        float ax = fabsf(til[i][j]) - 2e-5f;
        float nx = ax > 0.0f ? ax : 0.0f;
        x[i][j] = nx > 1.0f ? 1.0f : nx;
      }
  };
  auto stage = [&]() {  // m = I + x.*x/64 -> PE (R-plane), PF (T-plane)
    float m[4][4];
#pragma unroll
    for (int i = 0; i < 4; ++i)
#pragma unroll
      for (int j = 0; j < 4; ++j)
        m[i][j] = fmaf(x[i][j] * x[i][j], 0.015625f,
                       (r0 + i == c0 + j) ? 1.0f : 0.0f);
#pragma unroll
    for (int i = 0; i < 4; ++i)
      *(uint2*)(PE + o.prow[i]) =
          make_uint2(pk(m[i][0], m[i][1]), pk(m[i][2], m[i][3]));
#pragma unroll
    for (int j = 0; j < 4; ++j)
      *(uint2*)(PF + o.pcol[j]) =
          make_uint2(pk(m[0][j], m[1][j]), pk(m[2][j], m[3][j]));
    __syncthreads();
  };
  auto chain5 = [&]() {                    // sources: PE=R(m), PF=T(m)
    mm<true, false>(PE, PF, PD, PD, o);    // c1: m2  -> R only
    mm<true, true>(PD, PF, PE, PC, o);     // c2: m3 = m2*m -> (R3, T3)
    mm<true, true>(PE, PC, PD, PF, o);     // c3: m6 = m3^2
    mm<true, false>(PD, PF, PE, PE, o);    // c4: m12 -> R only
    mm<true, true>(PE, PC, PA, PB, o);     // c5: m15 = m12*m3 -> (PA,PB)
  };
  auto gradprox = [&]() {  // alpha from red (tr(m30) of x_i); T63 in PD
    float tr = red[0] + red[1];
    alpha = fmaf(0.01f, tr * 0.015625f - 1.0f, alpha);
    const float a2 = alpha * 0.03125f;  // 2*alpha/64
    float til[4][4];
#pragma unroll
    for (int i = 0; i < 4; ++i) {
      uint2 w = *(const uint2*)(PD + o.prow[i]);
      float pt[4] = {rlo(w.x), rhi(w.x), rlo(w.y), rhi(w.y)};
#pragma unroll
      for (int j = 0; j < 4; ++j) {
        float g = fmaf(a2 * x[i][j], pt[j], -sc[i][j]);
        til[i][j] = fmaf(-0.01f, g, x[i][j]);
      }
    }
    prox(til);
  };
  auto front = [&]() {
    mm<true, true, true>(PA, PB, PD, PE, o, red);  // f1: m30 (+free trace)
    mm<true, false>(PD, PE, PF, PF, o);            // f2: m60 -> R only
    mm<false, true>(PF, PC, PD, PD, o);            // f3: m63 -> T only (PD)
  };

  // ---- iteration 0: alpha == 0 -> grad = -scores ----
  {
    float til[4][4];
#pragma unroll
    for (int i = 0; i < 4; ++i)
#pragma unroll
      for (int j = 0; j < 4; ++j) til[i][j] = fmaf(0.01f, sc[i][j], x[i][j]);
    prox(til);
    stage();
    chain5();
  }
  // ---- iterations 1..48 ----
  for (int it = 0; it < 48; ++it) {
    front();
    gradprox();
    stage();
    chain5();
  }
  // ---- iteration 49: no trailing stage/chain ----
  front();
  gradprox();

  float* dst = out + (size_t)blockIdx.x * 4096;
#pragma unroll
  for (int i = 0; i < 4; ++i) {
    f32x4 v;
#pragma unroll
    for (int j = 0; j < 4; ++j) v[j] = (x[i][j] > 0.5f) ? x[i][j] : 0.0f;
    *(f32x4*)(dst + (r0 + i) * 64 + c0) = v;
  }
}

extern "C" void kernel_launch(void* const* d_in, const int* in_sizes, int n_in,
                              void* d_out, int out_size, void* d_ws,
                              size_t ws_size, hipStream_t stream) {
  const float* adj = (const float*)d_in[0];
  float* out = (float*)d_out;
  const int nbatch = in_sizes[0] / 4096;  // 512
  dag_iter_kernel<<<nbatch, 256, 0, stream>>>(adj, out);
}

// Round 9
// 260.311 us; speedup vs baseline: 2.1717x; 1.0287x over previous
//
#include <hip/hip_runtime.h>
#include <stdint.h>

// Each 64x64 matrix: bf16 planes in LDS, unpadded stride 64, XOR-swizzled:
//   element [r][c] at short-index  r*64 + (((c>>3) ^ (r&7))<<3) + (c&7)
//   R-plane: row-major (MFMA A-fragment = one b128)
//   T-plane: transposed (MFMA B-fragment = one b128)
// 6 fixed plane slots, 1-periodic schedule; all LDS addrs loop-invariant.
#define PL 4096  // shorts per plane

typedef unsigned int u32;
typedef unsigned short u16;
typedef float f32x4 __attribute__((ext_vector_type(4)));
typedef short short8 __attribute__((ext_vector_type(8)));

__device__ __forceinline__ u32 prm(u32 a, u32 b, u32 s) {
  return __builtin_amdgcn_perm(a, b, s);
}
__device__ __forceinline__ u32 pk(float f0, float f1) {  // {bf16 f0, bf16 f1}
  return prm(__float_as_uint(f1), __float_as_uint(f0), 0x07060302u);
}
__device__ __forceinline__ float rlo(u32 w) { return __uint_as_float(w << 16); }
__device__ __forceinline__ float rhi(u32 w) {
  return __uint_as_float(w & 0xffff0000u);
}

// Per-thread invariant LDS short-offsets (4-wave 2x2 quadrant split).
struct O {
  int ra[2][2];  // A-frag read [ti][q]
  int rb[2][2];  // B-frag read [tj][q]
  int sT[2][2];  // T-plane store for primary product tile (ti,tj)
  int sR[2][2];  // R-plane store for mirror product tile (ti,tj)
  int prow[4];   // patch addr: sidx(r0+i, c0), 4-elem run
  int pcol[4];   // patch addr: sidx(c0+j, r0), 4-elem run
};

// B-fragment register cache: the 4 b128 loads of one round's B-operand,
// reusable by any later round whose B-plane content is unchanged.
struct BF {
  short8 b0[2], b1[2];
};

__device__ __forceinline__ BF loadB(const u16* __restrict__ BT, const O& o) {
  BF f;
#pragma unroll
  for (int t = 0; t < 2; ++t) {
    f.b0[t] = *(const short8*)(BT + o.rb[t][0]);
    f.b1[t] = *(const short8*)(BT + o.rb[t][1]);
  }
  return f;
}

// C = A @ B (64x64 bf16). 4 waves, wave wv owns quadrant as 2x2 16x16 tiles.
// Primary (a x b) -> C^T-contiguous -> T-plane; mirror (b x a) -> R-plane.
// WR/WT gate dead planes. TR: diagonal waves (0,3) also compute sum R.*T of
// the loaded fragments (their a/b fragment index sets coincide element-for-
// element) = tr(A*B) -> tr(m30) for free when A=R15,B=T15.
// B-fragments come from a register cache. Dest planes != source planes.
// Trailing barrier.
template <bool WR, bool WT, bool TR = false>
__device__ __forceinline__ void mm_core(const u16* __restrict__ AR,
                                        const BF& bf, u16* __restrict__ CR,
                                        u16* __restrict__ CT, const O& o,
                                        float* red = nullptr) {
  short8 a0[2], a1[2];
#pragma unroll
  for (int t = 0; t < 2; ++t) {
    a0[t] = *(const short8*)(AR + o.ra[t][0]);
    a1[t] = *(const short8*)(AR + o.ra[t][1]);
  }
  if (TR) {
    const int tid = (int)threadIdx.x;
    const int wvv = tid >> 6;
    if (wvv == 0 || wvv == 3) {  // diagonal quadrants: frags element-aligned
      float part = 0.0f;
#pragma unroll
      for (int t = 0; t < 2; ++t) {
        const u32* ap0 = (const u32*)&a0[t];
        const u32* bp0 = (const u32*)&bf.b0[t];
        const u32* ap1 = (const u32*)&a1[t];
        const u32* bp1 = (const u32*)&bf.b1[t];
#pragma unroll
        for (int w = 0; w < 4; ++w) {
          part = fmaf(rlo(ap0[w]), rlo(bp0[w]), part);
          part = fmaf(rhi(ap0[w]), rhi(bp0[w]), part);
          part = fmaf(rlo(ap1[w]), rlo(bp1[w]), part);
          part = fmaf(rhi(ap1[w]), rhi(bp1[w]), part);
        }
      }
#pragma unroll
      for (int off = 1; off < 64; off <<= 1) part += __shfl_xor(part, off);
      if ((tid & 63) == 0) red[wvv == 0 ? 0 : 1] = part;
    }
  }
  const f32x4 Z = {0.0f, 0.0f, 0.0f, 0.0f};
#pragma unroll
  for (int ti = 0; ti < 2; ++ti)
#pragma unroll
    for (int tj = 0; tj < 2; ++tj) {
      if (WT) {
        f32x4 acc = __builtin_amdgcn_mfma_f32_16x16x32_bf16(a0[ti], bf.b0[tj],
                                                            Z, 0, 0, 0);
        acc = __builtin_amdgcn_mfma_f32_16x16x32_bf16(a1[ti], bf.b1[tj], acc,
                                                      0, 0, 0);
        *(uint2*)(CT + o.sT[ti][tj]) =
            make_uint2(pk(acc[0], acc[1]), pk(acc[2], acc[3]));
      }
      if (WR) {
        f32x4 acc = __builtin_amdgcn_mfma_f32_16x16x32_bf16(bf.b0[tj], a0[ti],
                                                            Z, 0, 0, 0);
        acc = __builtin_amdgcn_mfma_f32_16x16x32_bf16(bf.b1[tj], a1[ti], acc,
                                                      0, 0, 0);
        *(uint2*)(CR + o.sR[ti][tj]) =
            make_uint2(pk(acc[0], acc[1]), pk(acc[2], acc[3]));
      }
    }
  __syncthreads();
}

template <bool WR, bool WT, bool TR = false>
__device__ __forceinline__ void mm(const u16* __restrict__ AR,
                                   const u16* __restrict__ BT,
                                   u16* __restrict__ CR, u16* __restrict__ CT,
                                   const O& o, float* red = nullptr) {
  BF bf = loadB(BT, o);
  mm_core<WR, WT, TR>(AR, bf, CR, CT, o, red);
}

// One block (256 thr = 4 waves) per batch element; 2 blocks/CU. Thread owns a
// 4x4 patch (r0=(tid&15)*4, c0=(tid>>4)*4) for elementwise work.
//
// 1-periodic 6-slot schedule, invariant entering each iter:
//   PA=R15, PB=T15, PC=T3  (of current x)
//   f1 m30:(PA,PB)->(PD,PE) [+free trace into red]   f2 m60:(PD,PE)->PF [R]
//   f3 m63:(PF,cC=T3)->PD [T]
//   g: gradprox (alpha from red, T63 from PD); stage m(new x)->(PE=R, PF=T)
//   c1 m2:(PE,PF->cF)->PD [R]  c2 m3:(PD,cF)->(PE=R3, PC=T3)
//   c3 m6:(PE,PC->cC)->(PD,PF) c4 m12:(PD,PF)->PE [R]
//   c5 m15:(PE,cC)->(PA,PB)
// cC (T3) stays in registers from c3 through next iter's f3 (PC unchanged
// until the following c2); cF (T(m)) lives c1->c2 only.
__global__ __launch_bounds__(256, 2) void dag_iter_kernel(
    const float* __restrict__ adj, float* __restrict__ out) {
  __shared__ __align__(16) u16 BUF[6 * PL];
  __shared__ float red[2];
  u16* PA = BUF;
  u16* PB = BUF + PL;
  u16* PC = BUF + 2 * PL;
  u16* PD = BUF + 3 * PL;
  u16* PE = BUF + 4 * PL;
  u16* PF = BUF + 5 * PL;

  // De-phase the two co-resident blocks (b and b+256 share a CU): offset by
  // ~half a round so their LDS bursts interleave instead of colliding.
  if ((blockIdx.x >> 8) & 1) __builtin_amdgcn_s_sleep(11);

  const int tid = (int)threadIdx.x;
  const int lane = tid & 63;
  const int wv = tid >> 6;
  const int rh4 = (wv >> 1) << 1;
  const int ch4 = (wv & 1) << 1;
  const int l15 = lane & 15;
  const int grp = lane >> 4;
  const int l7 = l15 & 7;
  const int r0 = (tid & 15) << 2;
  const int c0 = (tid >> 4) << 2;

  O o;
#pragma unroll
  for (int q = 0; q < 2; ++q) {
    const int koff = (((q << 2) + grp) ^ l7) << 3;
#pragma unroll
    for (int t = 0; t < 2; ++t) {
      o.ra[t][q] = ((rh4 + t) * 16 + l15) * 64 + koff;
      o.rb[t][q] = ((ch4 + t) * 16 + l15) * 64 + koff;
    }
  }
#pragma unroll
  for (int ti = 0; ti < 2; ++ti)
#pragma unroll
    for (int tj = 0; tj < 2; ++tj) {
      const int a = rh4 + ti;
      const int b = ch4 + tj;
      o.sT[ti][tj] = (16 * b + l15) * 64 +
                     (((2 * a + (grp >> 1)) ^ l7) << 3) + ((grp & 1) << 2);
      o.sR[ti][tj] = (16 * a + l15) * 64 +
                     (((2 * b + (grp >> 1)) ^ l7) << 3) + ((grp & 1) << 2);
    }
#pragma unroll
  for (int i = 0; i < 4; ++i) {
    o.prow[i] =
        (r0 + i) * 64 + ((((c0 >> 3) ^ ((r0 + i) & 7))) << 3) + (c0 & 7);
    o.pcol[i] =
        (c0 + i) * 64 + ((((r0 >> 3) ^ ((c0 + i) & 7))) << 3) + (r0 & 7);
  }

  const float* src = adj + (size_t)blockIdx.x * 4096;
  float x[4][4], sc[4][4];
#pragma unroll
  for (int i = 0; i < 4; ++i) {
    f32x4 v = *(const f32x4*)(src + (r0 + i) * 64 + c0);
#pragma unroll
    for (int j = 0; j < 4; ++j) {
      x[i][j] = v[j];
      sc[i][j] = (v[j] > 0.5f) ? v[j] : 0.0f;
    }
  }
  float alpha = 0.0f;
  BF cC;  // register cache of T3's B-fragments (c3 -> c5 -> next f3)

  auto prox = [&](float til[4][4]) {
#pragma unroll
    for (int i = 0; i < 4; ++i)
#pragma unroll
      for (int j = 0; j < 4; ++j) {
        float ax = fabsf(til[i][j]) - 2e-5f;
        float nx = ax > 0.0f ? ax : 0.0f;
        x[i][j] = nx > 1.0f ? 1.0f : nx;
      }
  };
  auto stage = [&]() {  // m = I + x.*x/64 -> PE (R-plane), PF (T-plane)
    float m[4][4];
#pragma unroll
    for (int i = 0; i < 4; ++i)
#pragma unroll
      for (int j = 0; j < 4; ++j)
        m[i][j] = fmaf(x[i][j] * x[i][j], 0.015625f,
                       (r0 + i == c0 + j) ? 1.0f : 0.0f);
#pragma unroll
    for (int i = 0; i < 4; ++i)
      *(uint2*)(PE + o.prow[i]) =
          make_uint2(pk(m[i][0], m[i][1]), pk(m[i][2], m[i][3]));
#pragma unroll
    for (int j = 0; j < 4; ++j)
      *(uint2*)(PF + o.pcol[j]) =
          make_uint2(pk(m[0][j], m[1][j]), pk(m[2][j], m[3][j]));
    __syncthreads();
  };
  auto chain5 = [&]() {  // sources: PE=R(m), PF=T(m)
    BF cF = loadB(PF, o);                     // T(m), reused by c2
    mm_core<true, false>(PE, cF, PD, PD, o);  // c1: m2 -> R only
    mm_core<true, true>(PD, cF, PE, PC, o);   // c2: m3 -> (R3, T3)
    cC = loadB(PC, o);                        // T3, reused by c5 and next f3
    mm_core<true, true>(PE, cC, PD, PF, o);   // c3: m6 = m3^2
    mm<true, false>(PD, PF, PE, PE, o);       // c4: m12 -> R only
    mm_core<true, true>(PE, cC, PA, PB, o);   // c5: m15 -> (PA,PB)
  };
  auto gradprox = [&]() {  // alpha from red (tr(m30) of x_i); T63 in PD
    float tr = red[0] + red[1];
    alpha = fmaf(0.01f, tr * 0.015625f - 1.0f, alpha);
    const float a2 = alpha * 0.03125f;  // 2*alpha/64
    float til[4][4];
#pragma unroll
    for (int i = 0; i < 4; ++i) {
      uint2 w = *(const uint2*)(PD + o.prow[i]);
      float pt[4] = {rlo(w.x), rhi(w.x), rlo(w.y), rhi(w.y)};
#pragma unroll
      for (int j = 0; j < 4; ++j) {
        float g = fmaf(a2 * x[i][j], pt[j], -sc[i][j]);
        til[i][j] = fmaf(-0.01f, g, x[i][j]);
      }
    }
    prox(til);
  };
  auto front = [&]() {
    mm<true, true, true>(PA, PB, PD, PE, o, red);  // f1: m30 (+free trace)
    mm<true, false>(PD, PE, PF, PF, o);            // f2: m60 -> R only
    mm_core<false, true>(PF, cC, PD, PD, o);       // f3: m63 -> T only (PD)
  };

  // ---- iteration 0: alpha == 0 -> grad = -scores ----
  {
    float til[4][4];
#pragma unroll
    for (int i = 0; i < 4; ++i)
#pragma unroll
      for (int j = 0; j < 4; ++j) til[i][j] = fmaf(0.01f, sc[i][j], x[i][j]);
    prox(til);
    stage();
    chain5();
  }
  // ---- iterations 1..48 ----
  for (int it = 0; it < 48; ++it) {
    front();
    gradprox();
    stage();
    chain5();
  }
  // ---- iteration 49: no trailing stage/chain ----
  front();
  gradprox();

  float* dst = out + (size_t)blockIdx.x * 4096;
#pragma unroll
  for (int i = 0; i < 4; ++i) {
    f32x4 v;
#pragma unroll
    for (int j = 0; j < 4; ++j) v[j] = (x[i][j] > 0.5f) ? x[i][j] : 0.0f;
    *(f32x4*)(dst + (r0 + i) * 64 + c0) = v;
  }
}

extern "C" void kernel_launch(void* const* d_in, const int* in_sizes, int n_in,
                              void* d_out, int out_size, void* d_ws,
                              size_t ws_size, hipStream_t stream) {
  const float* adj = (const float*)d_in[0];
  float* out = (float*)d_out;
  const int nbatch = in_sizes[0] / 4096;  // 512
  dag_iter_kernel<<<nbatch, 256, 0, stream>>>(adj, out);
}